// Round 1
// baseline (207.811 us; speedup 1.0000x reference)
//
#include <hip/hip_runtime.h>
#include <hip/hip_bf16.h>

// 3D bilateral filter, radius 2 (125 taps), input (2,1,128,128,128) f32.
// v1: 8x8x8 output tile per 512-thread block, 12x12x12 LDS halo tile.
// Single fused exp2 per tap (spatial + range weights, log2e folded in).
// OOB handled by sentinel value 1e18 -> (x-xk)^2 huge -> exp2 -> 0 == mask.

#define RADIUS 2
#define N 128
#define TILE 8
#define LDS_DIM (TILE + 2 * RADIUS)            // 12
#define LDS_SIZE (LDS_DIM * LDS_DIM * LDS_DIM) // 1728

#if defined(__has_builtin)
#if __has_builtin(__builtin_amdgcn_exp2f)
#define EXP2(x) __builtin_amdgcn_exp2f(x)
#endif
#endif
#ifndef EXP2
#define EXP2(x) __expf((x) * 0.6931471805599453f)
#endif

#define LOG2E 1.4426950408889634f
#define BIG 1.0e18f

__global__ __launch_bounds__(512) void bilateral3d_kernel(
    const float* __restrict__ in, const float* __restrict__ p_sx,
    const float* __restrict__ p_sy, const float* __restrict__ p_sz,
    const float* __restrict__ p_cs, float* __restrict__ out) {
  __shared__ float s[LDS_SIZE];

  const int tid = threadIdx.x;
  const int x0 = blockIdx.x * TILE;
  const int y0 = blockIdx.y * TILE;
  const int zb = blockIdx.z;            // 0..31: low 4 bits = z-tile, bit 4 = batch
  const int z0 = (zb & 15) * TILE;
  const int b = zb >> 4;

  const float* vol = in + (size_t)b * N * N * N;

  // --- stage 12x12x12 halo tile into LDS (OOB -> sentinel) ---
  for (int i = tid; i < LDS_SIZE; i += 512) {
    int lx = i % LDS_DIM;
    int t = i / LDS_DIM;
    int ly = t % LDS_DIM;
    int lz = t / LDS_DIM;
    int gx = x0 + lx - RADIUS;
    int gy = y0 + ly - RADIUS;
    int gz = z0 + lz - RADIUS;
    float v = BIG;
    if ((unsigned)gx < N && (unsigned)gy < N && (unsigned)gz < N)
      v = vol[((size_t)gz * N + gy) * N + gx];
    s[i] = v;
  }
  __syncthreads();

  // --- per-thread voxel ---
  const int tx = tid & 7;
  const int ty = (tid >> 3) & 7;
  const int tz = tid >> 6;

  // coefficients (uniform): log2e folded so we can use raw exp2
  const float sx = p_sx[0], sy = p_sy[0], sz = p_sz[0], cs = p_cs[0];
  const float ax = LOG2E / (2.0f * sx * sx);
  const float ay = LOG2E / (2.0f * sy * sy);
  const float az = LOG2E / (2.0f * sz * sz);
  const float ac = LOG2E / (2.0f * cs * cs);

  const int cx = tx + RADIUS, cy = ty + RADIUS, cz = tz + RADIUS;
  const float x = s[(cz * LDS_DIM + cy) * LDS_DIM + cx];

  float num = 0.0f, den = 0.0f;
#pragma unroll
  for (int dz = -RADIUS; dz <= RADIUS; ++dz) {
    const float pz = az * (float)(dz * dz);
    const int rowz = (cz + dz) * LDS_DIM * LDS_DIM;
#pragma unroll
    for (int dy = -RADIUS; dy <= RADIUS; ++dy) {
      const float pzy = pz + ay * (float)(dy * dy);
      const int base = rowz + (cy + dy) * LDS_DIM + cx;
#pragma unroll
      for (int dx = -RADIUS; dx <= RADIUS; ++dx) {
        const float xk = s[base + dx];
        const float d = x - xk;
        const float w = EXP2(-(pzy + ax * (float)(dx * dx) + d * d * ac));
        den += w;
        num = fmaf(w, xk, num);
      }
    }
  }

  const int gx = x0 + tx, gy = y0 + ty, gz = z0 + tz;
  out[(((size_t)b * N + gz) * N + gy) * N + gx] = num / den;
}

extern "C" void kernel_launch(void* const* d_in, const int* in_sizes, int n_in,
                              void* d_out, int out_size, void* d_ws, size_t ws_size,
                              hipStream_t stream) {
  const float* in = (const float*)d_in[0];
  const float* sx = (const float*)d_in[1];
  const float* sy = (const float*)d_in[2];
  const float* sz = (const float*)d_in[3];
  const float* cs = (const float*)d_in[4];
  float* out = (float*)d_out;

  dim3 grid(N / TILE, N / TILE, (N / TILE) * 2);  // 16 x 16 x 32
  bilateral3d_kernel<<<grid, 512, 0, stream>>>(in, sx, sy, sz, cs, out);
}

// Round 2
// 165.739 us; speedup vs baseline: 1.2538x; 1.2538x over previous
//
#include <hip/hip_runtime.h>
#include <hip/hip_bf16.h>

// 3D bilateral filter, radius 2 (125 taps), input (2,1,128,128,128) f32.
// v2: 4 voxels/thread along x. 256-thread block computes a 16x8x8 tile,
// LDS halo tile 20x12x12 (rows left-aligned so each thread's 8-float tap
// window is two aligned ds_read_b128). 8 independent accumulator chains.
// One fused exp2 per tap; OOB via sentinel 1e18 -> w==0.

#define RADIUS 2
#define N 128
#define TX 16
#define TY 8
#define TZ 8
#define PITCH (TX + 2 * RADIUS)      // 20 floats per row, row start = logical x0-2
#define LYD (TY + 2 * RADIUS)        // 12
#define LZD (TZ + 2 * RADIUS)        // 12
#define LDS_SIZE (PITCH * LYD * LZD) // 2880 floats = 11.25 KB

#if defined(__has_builtin)
#if __has_builtin(__builtin_amdgcn_exp2f)
#define EXP2(x) __builtin_amdgcn_exp2f(x)
#endif
#endif
#ifndef EXP2
#define EXP2(x) __expf((x) * 0.6931471805599453f)
#endif

#define LOG2E 1.4426950408889634f
#define BIG 1.0e18f

__global__ __launch_bounds__(256) void bilateral3d_kernel(
    const float* __restrict__ in, const float* __restrict__ p_sx,
    const float* __restrict__ p_sy, const float* __restrict__ p_sz,
    const float* __restrict__ p_cs, float* __restrict__ out) {
  __shared__ float s[LDS_SIZE];

  const int tid = threadIdx.x;
  const int x0 = blockIdx.x * TX;
  const int y0 = blockIdx.y * TY;
  const int zb = blockIdx.z;  // low 4 bits = z-tile, bit 4 = batch
  const int z0 = (zb & 15) * TZ;
  const int b = zb >> 4;

  const float* vol = in + (size_t)b * (N * N * N);

  // --- stage 20x12x12 halo tile (OOB -> sentinel) ---
  for (int i = tid; i < LDS_SIZE; i += 256) {
    int lx = i % PITCH;
    int t = i / PITCH;
    int ly = t % LYD;
    int lz = t / LYD;
    int gx = x0 + lx - RADIUS;
    int gy = y0 + ly - RADIUS;
    int gz = z0 + lz - RADIUS;
    float v = BIG;
    if ((unsigned)gx < N && (unsigned)gy < N && (unsigned)gz < N)
      v = vol[((size_t)gz * N + gy) * N + gx];
    s[i] = v;
  }
  __syncthreads();

  const int tx = tid & 3;         // x-group: voxels x0+4tx .. x0+4tx+3
  const int ty = (tid >> 2) & 7;
  const int tz = tid >> 5;

  const float sxv = p_sx[0], syv = p_sy[0], szv = p_sz[0], csv = p_cs[0];
  const float AX = LOG2E / (2.0f * sxv * sxv);
  const float AY = LOG2E / (2.0f * syv * syv);
  const float AZ = LOG2E / (2.0f * szv * szv);
  const float NAC = -LOG2E / (2.0f * csv * csv);
  const float AX4 = 4.0f * AX;

  const int xw = 4 * tx;  // word offset within row of this thread's tap window

  // center values: f[v+2] of the (dz=0,dy=0) row
  const int cbase = ((tz + RADIUS) * LYD + (ty + RADIUS)) * PITCH + xw;
  const float4 CA = *(const float4*)&s[cbase];
  const float4 CB = *(const float4*)&s[cbase + 4];
  const float xc0 = CA.z, xc1 = CA.w, xc2 = CB.x, xc3 = CB.y;

  float n0 = 0, n1 = 0, n2 = 0, n3 = 0;
  float e0 = 0, e1 = 0, e2 = 0, e3 = 0;  // denominators

#define TAP(XC, FV, CC, NN, DD)                \
  {                                            \
    float _d = (XC) - (FV);                    \
    float _e = fmaf(_d * _d, NAC, (CC));       \
    float _w = EXP2(_e);                       \
    DD += _w;                                  \
    NN = fmaf(_w, (FV), NN);                   \
  }

#pragma unroll 1
  for (int dz = -RADIUS; dz <= RADIUS; ++dz) {
    const float pz = AZ * (float)(dz * dz);
    const int zrow = (tz + RADIUS + dz) * LYD;
#pragma unroll 1
    for (int dy = -RADIUS; dy <= RADIUS; ++dy) {
      const float npzy = -(pz + AY * (float)(dy * dy));
      const int rb = (zrow + (ty + RADIUS + dy)) * PITCH + xw;
      const float4 A = *(const float4*)&s[rb];
      const float4 B = *(const float4*)&s[rb + 4];
      const float f0 = A.x, f1 = A.y, f2 = A.z, f3 = A.w;
      const float f4 = B.x, f5 = B.y, f6 = B.z, f7 = B.w;
      const float cm4 = npzy - AX4;  // dx = +/-2
      const float cm1 = npzy - AX;   // dx = +/-1

      // dx = -2
      TAP(xc0, f0, cm4, n0, e0)
      TAP(xc1, f1, cm4, n1, e1)
      TAP(xc2, f2, cm4, n2, e2)
      TAP(xc3, f3, cm4, n3, e3)
      // dx = -1
      TAP(xc0, f1, cm1, n0, e0)
      TAP(xc1, f2, cm1, n1, e1)
      TAP(xc2, f3, cm1, n2, e2)
      TAP(xc3, f4, cm1, n3, e3)
      // dx = 0
      TAP(xc0, f2, npzy, n0, e0)
      TAP(xc1, f3, npzy, n1, e1)
      TAP(xc2, f4, npzy, n2, e2)
      TAP(xc3, f5, npzy, n3, e3)
      // dx = +1
      TAP(xc0, f3, cm1, n0, e0)
      TAP(xc1, f4, cm1, n1, e1)
      TAP(xc2, f5, cm1, n2, e2)
      TAP(xc3, f6, cm1, n3, e3)
      // dx = +2
      TAP(xc0, f4, cm4, n0, e0)
      TAP(xc1, f5, cm4, n1, e1)
      TAP(xc2, f6, cm4, n2, e2)
      TAP(xc3, f7, cm4, n3, e3)
    }
  }

  float4 r;
  r.x = n0 / e0;
  r.y = n1 / e1;
  r.z = n2 / e2;
  r.w = n3 / e3;

  const int gz = z0 + tz, gy = y0 + ty;
  *(float4*)&out[(((size_t)b * N + gz) * N + gy) * N + (x0 + xw)] = r;
}

extern "C" void kernel_launch(void* const* d_in, const int* in_sizes, int n_in,
                              void* d_out, int out_size, void* d_ws, size_t ws_size,
                              hipStream_t stream) {
  const float* in = (const float*)d_in[0];
  const float* sx = (const float*)d_in[1];
  const float* sy = (const float*)d_in[2];
  const float* sz = (const float*)d_in[3];
  const float* cs = (const float*)d_in[4];
  float* out = (float*)d_out;

  dim3 grid(N / TX, N / TY, (N / TZ) * 2);  // 8 x 16 x 32
  bilateral3d_kernel<<<grid, 256, 0, stream>>>(in, sx, sy, sz, cs, out);
}

// Round 3
// 164.174 us; speedup vs baseline: 1.2658x; 1.0095x over previous
//
#include <hip/hip_runtime.h>
#include <hip/hip_bf16.h>

// 3D bilateral filter, radius 2 (125 taps), input (2,1,128,128,128) f32.
// v3: v2 + __launch_bounds__(256,4) to stop the allocator squeezing into
// 32 VGPRs (v2 showed remat/mov overhead ~6 inst/tap), + full dy unroll so
// all 10 ds_read_b128 per dz-slice hoist and schedule against the FMA/exp
// stream. 4 voxels/thread along x; 8 independent accumulator chains.
// One fused exp2 per tap; OOB via sentinel 1e18 -> w==0.

#define RADIUS 2
#define N 128
#define TX 16
#define TY 8
#define TZ 8
#define PITCH (TX + 2 * RADIUS)      // 20 floats per row (4-word aligned rows)
#define LYD (TY + 2 * RADIUS)        // 12
#define LZD (TZ + 2 * RADIUS)        // 12
#define LDS_SIZE (PITCH * LYD * LZD) // 2880 floats = 11.25 KB

#if defined(__has_builtin)
#if __has_builtin(__builtin_amdgcn_exp2f)
#define EXP2(x) __builtin_amdgcn_exp2f(x)
#endif
#endif
#ifndef EXP2
#define EXP2(x) __expf((x) * 0.6931471805599453f)
#endif

#define LOG2E 1.4426950408889634f
#define BIG 1.0e18f

__global__ __launch_bounds__(256, 4) void bilateral3d_kernel(
    const float* __restrict__ in, const float* __restrict__ p_sx,
    const float* __restrict__ p_sy, const float* __restrict__ p_sz,
    const float* __restrict__ p_cs, float* __restrict__ out) {
  __shared__ float s[LDS_SIZE];

  const int tid = threadIdx.x;
  const int x0 = blockIdx.x * TX;
  const int y0 = blockIdx.y * TY;
  const int zb = blockIdx.z;  // low 4 bits = z-tile, bit 4 = batch
  const int z0 = (zb & 15) * TZ;
  const int b = zb >> 4;

  const float* vol = in + (size_t)b * (N * N * N);

  // --- stage 20x12x12 halo tile (OOB -> sentinel) ---
  for (int i = tid; i < LDS_SIZE; i += 256) {
    int lx = i % PITCH;
    int t = i / PITCH;
    int ly = t % LYD;
    int lz = t / LYD;
    int gx = x0 + lx - RADIUS;
    int gy = y0 + ly - RADIUS;
    int gz = z0 + lz - RADIUS;
    float v = BIG;
    if ((unsigned)gx < N && (unsigned)gy < N && (unsigned)gz < N)
      v = vol[((size_t)gz * N + gy) * N + gx];
    s[i] = v;
  }
  __syncthreads();

  const int tx = tid & 3;         // x-group: voxels x0+4tx .. x0+4tx+3
  const int ty = (tid >> 2) & 7;
  const int tz = tid >> 5;

  const float sxv = p_sx[0], syv = p_sy[0], szv = p_sz[0], csv = p_cs[0];
  const float AX = LOG2E / (2.0f * sxv * sxv);
  const float AY = LOG2E / (2.0f * syv * syv);
  const float AZ = LOG2E / (2.0f * szv * szv);
  const float NAC = -LOG2E / (2.0f * csv * csv);
  const float AX4 = 4.0f * AX;

  const int xw = 4 * tx;  // word offset within row of this thread's tap window

  // center values: words [xw+2 .. xw+5] of the (dz=0,dy=0) row
  const int cbase = ((tz + RADIUS) * LYD + (ty + RADIUS)) * PITCH + xw;
  const float4 CA = *(const float4*)&s[cbase];
  const float4 CB = *(const float4*)&s[cbase + 4];
  const float xc0 = CA.z, xc1 = CA.w, xc2 = CB.x, xc3 = CB.y;

  float n0 = 0, n1 = 0, n2 = 0, n3 = 0;
  float e0 = 0, e1 = 0, e2 = 0, e3 = 0;  // denominators

#define TAP(XC, FV, CC, NN, DD)                \
  {                                            \
    float _d = (XC) - (FV);                    \
    float _e = fmaf(_d * _d, NAC, (CC));       \
    float _w = EXP2(_e);                       \
    DD += _w;                                  \
    NN = fmaf(_w, (FV), NN);                   \
  }

#pragma unroll 1
  for (int dz = -RADIUS; dz <= RADIUS; ++dz) {
    const float pz = AZ * (float)(dz * dz);
    const int zrow = (tz + RADIUS + dz) * LYD;
#pragma unroll
    for (int dy = -RADIUS; dy <= RADIUS; ++dy) {
      const float npzy = -(pz + AY * (float)(dy * dy));
      const int rb = (zrow + (ty + RADIUS + dy)) * PITCH + xw;
      const float4 A = *(const float4*)&s[rb];
      const float4 B = *(const float4*)&s[rb + 4];
      const float f0 = A.x, f1 = A.y, f2 = A.z, f3 = A.w;
      const float f4 = B.x, f5 = B.y, f6 = B.z, f7 = B.w;
      const float cm4 = npzy - AX4;  // dx = +/-2
      const float cm1 = npzy - AX;   // dx = +/-1

      // dx = -2
      TAP(xc0, f0, cm4, n0, e0)
      TAP(xc1, f1, cm4, n1, e1)
      TAP(xc2, f2, cm4, n2, e2)
      TAP(xc3, f3, cm4, n3, e3)
      // dx = -1
      TAP(xc0, f1, cm1, n0, e0)
      TAP(xc1, f2, cm1, n1, e1)
      TAP(xc2, f3, cm1, n2, e2)
      TAP(xc3, f4, cm1, n3, e3)
      // dx = 0
      TAP(xc0, f2, npzy, n0, e0)
      TAP(xc1, f3, npzy, n1, e1)
      TAP(xc2, f4, npzy, n2, e2)
      TAP(xc3, f5, npzy, n3, e3)
      // dx = +1
      TAP(xc0, f3, cm1, n0, e0)
      TAP(xc1, f4, cm1, n1, e1)
      TAP(xc2, f5, cm1, n2, e2)
      TAP(xc3, f6, cm1, n3, e3)
      // dx = +2
      TAP(xc0, f4, cm4, n0, e0)
      TAP(xc1, f5, cm4, n1, e1)
      TAP(xc2, f6, cm4, n2, e2)
      TAP(xc3, f7, cm4, n3, e3)
    }
  }

  float4 r;
  r.x = n0 / e0;
  r.y = n1 / e1;
  r.z = n2 / e2;
  r.w = n3 / e3;

  const int gz = z0 + tz, gy = y0 + ty;
  *(float4*)&out[(((size_t)b * N + gz) * N + gy) * N + (x0 + xw)] = r;
}

extern "C" void kernel_launch(void* const* d_in, const int* in_sizes, int n_in,
                              void* d_out, int out_size, void* d_ws, size_t ws_size,
                              hipStream_t stream) {
  const float* in = (const float*)d_in[0];
  const float* sx = (const float*)d_in[1];
  const float* sy = (const float*)d_in[2];
  const float* sz = (const float*)d_in[3];
  const float* cs = (const float*)d_in[4];
  float* out = (float*)d_out;

  dim3 grid(N / TX, N / TY, (N / TZ) * 2);  // 8 x 16 x 32
  bilateral3d_kernel<<<grid, 256, 0, stream>>>(in, sx, sy, sz, cs, out);
}